// Round 3
// baseline (542.814 us; speedup 1.0000x reference)
//
#include <hip/hip_runtime.h>

#define T 4
#define D 1024
#define NN 256
#define K 64
#define V 32000
#define VK (V*K)            // 2048000
#define TD (T*D)            // 4096
#define NTOK (TD*NN)        // 1048576
#define NG 1000             // V/32 w-groups per t
#define NBINS (T*NG)        // 4000

__device__ __forceinline__ float jexp(float x) {
    x = fminf(fmaxf(x, -700.0f), 700.0f);
    return fmaxf(expf(x), 1e-6f);
}

// ---------------- eta SGLD update: one wave per (t,d) row ----------------
__global__ void eta_kernel(const float* __restrict__ eta,
                           const float* __restrict__ alpha,
                           const float* __restrict__ CDK,
                           const float* __restrict__ noise_eta,
                           float* __restrict__ eta_new)
{
    int wave = threadIdx.x >> 6;
    int lane = threadIdx.x & 63;
    int r = blockIdx.x * 4 + wave;
    int t = r >> 10;
    float x = eta[r * K + lane];
    float m = x;
    #pragma unroll
    for (int off = 32; off >= 1; off >>= 1)
        m = fmaxf(m, __shfl_xor(m, off, 64));
    float e = expf(x - m);
    float s = e;
    #pragma unroll
    for (int off = 32; off >= 1; off >>= 1)
        s += __shfl_xor(s, off, 64);
    float grad  = CDK[r * K + lane] - (float)NN * (e / s);
    float prior = alpha[t * K + lane] - x;
    eta_new[r * K + lane] = x + 0.005f * (grad + prior) + noise_eta[r] * 0.01f;
}

// ---------------- histogram over (t, w>>5) bins ----------------
__global__ void hist_kernel(const int* __restrict__ W, int* __restrict__ hist)
{
    #pragma unroll
    for (int j = 0; j < 4; ++j) {
        int i = blockIdx.x * 1024 + j * 256 + threadIdx.x;   // < NTOK
        int w = W[i];
        int t = i >> 18;                                     // D*NN = 2^18
        atomicAdd(&hist[t * NG + (w >> 5)], 1);
    }
}

// ---------------- exclusive scan of 4000 bins (single block) ----------------
__global__ void scan_kernel(const int* __restrict__ hist,
                            int* __restrict__ starts, int* __restrict__ cursors)
{
    __shared__ int sm[1024];
    __shared__ int carry;
    if (threadIdx.x == 0) carry = 0;
    __syncthreads();
    for (int c = 0; c < NBINS; c += 1024) {
        int i = c + threadIdx.x;
        int orig = (i < NBINS) ? hist[i] : 0;
        int v = orig;
        sm[threadIdx.x] = v;
        __syncthreads();
        for (int off = 1; off < 1024; off <<= 1) {
            int add = (threadIdx.x >= off) ? sm[threadIdx.x - off] : 0;
            __syncthreads();
            v += add;
            sm[threadIdx.x] = v;
            __syncthreads();
        }
        int excl = carry + v - orig;
        if (i < NBINS) { starts[i] = excl; cursors[i] = excl; }
        __syncthreads();
        if (threadIdx.x == 1023) carry += sm[1023];
        __syncthreads();
    }
}

// ---------------- scatter token records into w-sorted bins ----------------
// one block per doc; records are 16B: packed ids + the two MH uniforms
__global__ void scatter_kernel(const int* __restrict__ W, const int* __restrict__ Z,
                               const int* __restrict__ pwi, const int* __restrict__ ptop,
                               const float* __restrict__ u,
                               int* __restrict__ cursors, int4* __restrict__ records)
{
    int r = blockIdx.x;            // doc = t*D + d
    int t = r >> 10;
    int n = threadIdx.x;
    __shared__ int zsh[NN];
    int pre = Z[r * NN + n];
    zsh[n] = pre;
    __syncthreads();
    int w  = W[r * NN + n];
    int p1 = zsh[pwi[r * NN + n]];
    int pt = ptop[r * NN + n];
    float2 uu = ((const float2*)u)[r * NN + n];
    int bin = t * NG + (w >> 5);
    int pos = atomicAdd(&cursors[bin], 1);
    int a = (pre << 20) | (r << 8) | n;          // pre:6 @20, doc:12 @8, n:8 @0
    int b = (w << 12) | (p1 << 6) | pt;          // w:15 @12, prop1:6 @6, pt:6 @0
    records[pos] = make_int4(a, b, __float_as_int(uu.x), __float_as_int(uu.y));
}

// ---------------- MH decisions + CWK scatter, in w-sorted order ----------------
__global__ void process_kernel(const int4* __restrict__ records,
                               const float* __restrict__ phi,
                               const float* __restrict__ eta_new,
                               float* __restrict__ CWK_new,
                               float* __restrict__ z_out)
{
    int i = blockIdx.x * 256 + threadIdx.x;      // < NTOK
    int4 rec = records[i];
    int a = rec.x, b = rec.y;
    float u0 = __int_as_float(rec.z), u1 = __int_as_float(rec.w);
    int pre = (a >> 20) & 63;
    int r   = (a >> 8) & 4095;
    int n   = a & 255;
    int w   = (b >> 12) & 32767;
    int p1  = (b >> 6) & 63;
    int pt  = b & 63;
    int t   = r >> 10;

    const float* prow = phi + ((size_t)t * V + w) * K;   // L2-resident (w-sorted)
    float pa = prow[p1];
    float pb = prow[pre];
    float a1 = jexp(pa) / jexp(pb);
    int k1 = (u0 < a1) ? p1 : pre;

    float ea = eta_new[r * K + pt];              // random over 1MB -> L2
    float ek = eta_new[r * K + k1];
    float a2 = jexp(ea) / jexp(ek);
    int z = (u1 < a2) ? pt : k1;

    z_out[r * NN + n] = (float)z;                // scattered 4B over 4MB -> L2
    if (z != pre) {                              // exact integer fp adds, commutative
        float* crow = CWK_new + ((size_t)t * V + w) * K;
        atomicAdd(&crow[z],   1.0f);
        atomicAdd(&crow[pre], -1.0f);
    }
}

// ---------------- doc-centric CDK/CK finalize from z_out ----------------
__global__ void finalize_kernel(const int* __restrict__ Z,
                                const float* __restrict__ z_out,
                                const float* __restrict__ CDK,
                                float* __restrict__ CDK_new,
                                float* __restrict__ CK_new)
{
    int r = blockIdx.x;
    int t = r >> 10;
    int n = threadIdx.x;
    __shared__ int hist[K];
    if (n < K) hist[n] = 0;
    __syncthreads();
    int pre = Z[r * NN + n];
    int z = (int)z_out[r * NN + n];
    if (z != pre) {
        atomicAdd(&hist[z], 1);
        atomicAdd(&hist[pre], -1);
    }
    __syncthreads();
    if (n < K) {
        int h = hist[n];
        CDK_new[r * K + n] = CDK[r * K + n] + (float)h;
        if (h) atomicAdd(&CK_new[t * K + n], (float)h);
    }
}

// ---------------- per-(t,k) sum of exp(phi[t,:,k]) over V ----------------
__global__ void phi_colsum_kernel(const float* __restrict__ phi,
                                  float* __restrict__ S)
{
    int blk = blockIdx.x;
    int t = blk / 250;
    int vbase = (blk % 250) * 128;
    int k = threadIdx.x & 63;
    int rr = threadIdx.x >> 6;
    const float* base = phi + (size_t)t * VK;
    float s = 0.0f;
    #pragma unroll 4
    for (int it = 0; it < 32; ++it) {
        int v = vbase + it * 4 + rr;
        s += expf(base[v * K + k]);
    }
    __shared__ float sm[256];
    sm[threadIdx.x] = s;
    __syncthreads();
    if (threadIdx.x < 64) {
        float tot = sm[threadIdx.x] + sm[threadIdx.x + 64] +
                    sm[threadIdx.x + 128] + sm[threadIdx.x + 192];
        atomicAdd(&S[t * K + k], tot);
    }
}

// ---------------- phi SGLD update, all 4 time steps in registers ----------------
__global__ void phi_update_kernel(const float* __restrict__ phi,
                                  const float* __restrict__ CWKn,
                                  const float* __restrict__ CKn,
                                  const float* __restrict__ S,
                                  const float* __restrict__ noise_phi,
                                  float* __restrict__ phi_new)
{
    int idx = blockIdx.x * 256 + threadIdx.x;
    int k = idx & 63;
    const float eps = 0.01f;
    const float half_eps = 0.005f;
    const float sig = 1.0f / 1.01f;

    float p0 = phi[idx];
    float p1 = phi[idx + VK];
    float p2 = phi[idx + 2 * VK];
    float p3 = phi[idx + 3 * VK];

    float g0 = CWKn[idx]          - CKn[k]         * (expf(p0) / S[k]);
    float g1 = CWKn[idx + VK]     - CKn[K + k]     * (expf(p1) / S[K + k]);
    float g2 = CWKn[idx + 2 * VK] - CKn[2 * K + k] * (expf(p2) / S[2 * K + k]);
    float g3 = CWKn[idx + 3 * VK] - CKn[3 * K + k] * (expf(p3) / S[3 * K + k]);

    float r0 = p0 + half_eps * (g0 + 2.0f * p1 * sig - 2.0f * p0) + noise_phi[0] * eps;
    float r1 = p1 + half_eps * (g1 + p2 + r0 - 2.0f * p1)         + noise_phi[1] * eps;
    float r2 = p2 + half_eps * (g2 + p3 + r1 - 2.0f * p2)         + noise_phi[2] * eps;
    float r3 = p3 + half_eps * (g3 + r2 - p3)                      + noise_phi[3] * eps;

    phi_new[idx]          = r0;
    phi_new[idx + VK]     = r1;
    phi_new[idx + 2 * VK] = r2;
    phi_new[idx + 3 * VK] = r3;
}

extern "C" void kernel_launch(void* const* d_in, const int* in_sizes, int n_in,
                              void* d_out, int out_size, void* d_ws, size_t ws_size,
                              hipStream_t stream)
{
    const int*   W         = (const int*)  d_in[0];
    const int*   Z         = (const int*)  d_in[1];
    const int*   pwi       = (const int*)  d_in[2];
    const int*   ptop      = (const int*)  d_in[3];
    const float* u_mh      = (const float*)d_in[4];
    const float* noise_eta = (const float*)d_in[5];
    const float* noise_phi = (const float*)d_in[6];
    const float* alpha     = (const float*)d_in[7];
    const float* phi       = (const float*)d_in[8];
    const float* eta       = (const float*)d_in[9];
    const float* CDK       = (const float*)d_in[10];
    const float* CWK       = (const float*)d_in[11];
    const float* CK        = (const float*)d_in[12];

    float* out     = (float*)d_out;
    float* eta_new = out;                               // T*D*K
    float* phi_new = out + 262144;                      // T*V*K
    float* CDK_new = out + 8454144;                     // T*D*K
    float* CWK_new = out + 8716288;                     // T*V*K
    float* CK_new  = out + 16908288;                    // T*K
    float* z_out   = out + 16908544;                    // T*D*N

    // workspace layout: [hist 4000][starts 4000][cursors 4000][S 256] | records @64KB
    int*   hist    = (int*)d_ws;
    int*   starts  = hist + 4096;
    int*   cursors = starts + 4096;
    float* S       = (float*)(cursors + 4096);
    int4*  records = (int4*)((char*)d_ws + 65536);      // NTOK * 16B = 16 MB

    hipMemsetAsync(d_ws, 0, 65536, stream);
    hipMemcpyAsync(CWK_new, CWK, (size_t)T * VK * sizeof(float),
                   hipMemcpyDeviceToDevice, stream);
    hipMemcpyAsync(CK_new, CK, T * K * sizeof(float),
                   hipMemcpyDeviceToDevice, stream);

    eta_kernel<<<TD / 4, 256, 0, stream>>>(eta, alpha, CDK, noise_eta, eta_new);
    hist_kernel<<<NTOK / 1024, 256, 0, stream>>>(W, hist);
    scan_kernel<<<1, 1024, 0, stream>>>(hist, starts, cursors);
    scatter_kernel<<<TD, 256, 0, stream>>>(W, Z, pwi, ptop, u_mh, cursors, records);
    process_kernel<<<NTOK / 256, 256, 0, stream>>>(records, phi, eta_new,
                                                   CWK_new, z_out);
    finalize_kernel<<<TD, 256, 0, stream>>>(Z, z_out, CDK, CDK_new, CK_new);
    phi_colsum_kernel<<<T * 250, 256, 0, stream>>>(phi, S);
    phi_update_kernel<<<VK / 256, 256, 0, stream>>>(phi, CWK_new, CK_new, S,
                                                    noise_phi, phi_new);
}

// Round 4
// 425.458 us; speedup vs baseline: 1.2758x; 1.2758x over previous
//
#include <hip/hip_runtime.h>

#define T 4
#define D 1024
#define NN 256
#define K 64
#define V 32000
#define VK (V*K)            // 2048000
#define TD (T*D)            // 4096
#define NTOK (TD*NN)        // 1048576
#define NG 1000             // V/32 w-groups per t
#define NBINS (T*NG)        // 4000

__device__ __forceinline__ float jexp(float x) {
    x = fminf(fmaxf(x, -700.0f), 700.0f);
    return fmaxf(expf(x), 1e-6f);
}

// ---------------- eta SGLD update: one wave per (t,d) row ----------------
__global__ void eta_kernel(const float* __restrict__ eta,
                           const float* __restrict__ alpha,
                           const float* __restrict__ CDK,
                           const float* __restrict__ noise_eta,
                           float* __restrict__ eta_new)
{
    int wave = threadIdx.x >> 6;
    int lane = threadIdx.x & 63;
    int r = blockIdx.x * 4 + wave;
    int t = r >> 10;
    float x = eta[r * K + lane];
    float m = x;
    #pragma unroll
    for (int off = 32; off >= 1; off >>= 1)
        m = fmaxf(m, __shfl_xor(m, off, 64));
    float e = expf(x - m);
    float s = e;
    #pragma unroll
    for (int off = 32; off >= 1; off >>= 1)
        s += __shfl_xor(s, off, 64);
    float grad  = CDK[r * K + lane] - (float)NN * (e / s);
    float prior = alpha[t * K + lane] - x;
    eta_new[r * K + lane] = x + 0.005f * (grad + prior) + noise_eta[r] * 0.01f;
}

// ---------------- LDS-privatized histogram over (t, w>>5) bins ----------------
// 64 blocks x 16384 tokens; flush with wave-coalesced global adds.
__global__ __launch_bounds__(256) void hist1_kernel(const int* __restrict__ W,
                                                    int* __restrict__ hist)
{
    __shared__ int h[NBINS];
    int tid = threadIdx.x;
    for (int i = tid; i < NBINS; i += 256) h[i] = 0;
    __syncthreads();
    int tok0 = blockIdx.x * 16384;
    for (int i = 0; i < 64; ++i) {
        int idx = tok0 + i * 256 + tid;
        int w = W[idx];
        atomicAdd(&h[(idx >> 18) * NG + (w >> 5)], 1);   // D*NN = 2^18
    }
    __syncthreads();
    for (int i = tid; i < NBINS; i += 256) {
        int c = h[i];
        if (c) atomicAdd(&hist[i], c);                   // consecutive addrs/wave
    }
}

// ---------------- exclusive scan of 4000 bins (single block) ----------------
__global__ void scan_kernel(const int* __restrict__ hist,
                            int* __restrict__ starts, int* __restrict__ cursors)
{
    __shared__ int sm[1024];
    __shared__ int carry;
    if (threadIdx.x == 0) carry = 0;
    __syncthreads();
    for (int c = 0; c < NBINS; c += 1024) {
        int i = c + threadIdx.x;
        int orig = (i < NBINS) ? hist[i] : 0;
        int v = orig;
        sm[threadIdx.x] = v;
        __syncthreads();
        for (int off = 1; off < 1024; off <<= 1) {
            int add = (threadIdx.x >= off) ? sm[threadIdx.x - off] : 0;
            __syncthreads();
            v += add;
            sm[threadIdx.x] = v;
            __syncthreads();
        }
        int excl = carry + v - orig;
        if (i < NBINS) { starts[i] = excl; cursors[i] = excl; }
        __syncthreads();
        if (threadIdx.x == 1023) carry += sm[1023];
        __syncthreads();
    }
}

// ---------------- scatter records: per-block bin reservation, no per-token
// global atomics. 64 blocks x 64 docs each.
__global__ __launch_bounds__(256) void scatter2_kernel(
        const int* __restrict__ W, const int* __restrict__ Z,
        const int* __restrict__ pwi, const int* __restrict__ ptop,
        const float* __restrict__ u,
        int* __restrict__ cursors, int4* __restrict__ records)
{
    __shared__ int hist_l[NBINS];    // 16 KB: per-block counts, then ranks
    __shared__ int base_l[NBINS];    // 16 KB
    __shared__ int zsh[NN];
    int tid = threadIdx.x;
    for (int i = tid; i < NBINS; i += 256) hist_l[i] = 0;
    __syncthreads();
    int tok0 = blockIdx.x * 16384;
    for (int i = 0; i < 64; ++i) {
        int idx = tok0 + i * 256 + tid;
        int w = W[idx];
        atomicAdd(&hist_l[(idx >> 18) * NG + (w >> 5)], 1);
    }
    __syncthreads();
    for (int i = tid; i < NBINS; i += 256) {
        int c = hist_l[i];
        base_l[i] = c ? atomicAdd(&cursors[i], c) : 0;   // 1 atomic/(block,bin)
        hist_l[i] = 0;                                   // becomes running rank
    }
    __syncthreads();
    int doc0 = blockIdx.x * 64;
    for (int i = 0; i < 64; ++i) {
        int r = doc0 + i;
        int t = r >> 10;
        zsh[tid] = Z[r * NN + tid];
        __syncthreads();
        int n = tid;
        int w  = W[r * NN + n];
        int p1 = zsh[pwi[r * NN + n]];
        int pt = ptop[r * NN + n];
        int pre = zsh[n];
        float2 uu = ((const float2*)u)[r * NN + n];
        int bin = t * NG + (w >> 5);
        int rank = atomicAdd(&hist_l[bin], 1);           // LDS atomic: fast
        int pos = base_l[bin] + rank;
        int a = (pre << 20) | (r << 8) | n;
        int b = (w << 12) | (p1 << 6) | pt;
        records[pos] = make_int4(a, b, __float_as_int(uu.x), __float_as_int(uu.y));
        __syncthreads();                                 // protect zsh reuse
    }
}

// ---------------- MH decisions + CWK delta, one block per (t, 32-word window).
// Covers every CWK row exactly once -> fuses the CWK copy; zero global atomics.
__global__ __launch_bounds__(256) void process_kernel(
        const int4* __restrict__ records, const float* __restrict__ phi,
        const float* __restrict__ CWK, const float* __restrict__ eta_new,
        const int* __restrict__ hist, const int* __restrict__ starts,
        float* __restrict__ CWK_new, float* __restrict__ z_out)
{
    __shared__ float phl[2048];      // phi window: 32 words x 64 topics
    __shared__ int   acc[2048];      // integer CWK deltas
    int b = blockIdx.x;
    int t = b / NG;
    int wg = b % NG;
    size_t rowbase = ((size_t)t * V + (size_t)wg * 32) * K;
    int tid = threadIdx.x;
    #pragma unroll
    for (int i = 0; i < 8; ++i) {
        phl[i * 256 + tid] = phi[rowbase + i * 256 + tid];
        acc[i * 256 + tid] = 0;
    }
    __syncthreads();
    int cnt = hist[b], s0 = starts[b];
    for (int i = tid; i < cnt; i += 256) {
        int4 rec = records[s0 + i];
        int a = rec.x, bb = rec.y;
        float u0 = __int_as_float(rec.z), u1 = __int_as_float(rec.w);
        int pre = (a >> 20) & 63;
        int r   = (a >> 8) & 4095;
        int n   = a & 255;
        int w   = (bb >> 12) & 32767;
        int p1  = (bb >> 6) & 63;
        int pt  = bb & 63;
        int wl  = (w & 31) << 6;
        float pa = phl[wl | p1], pb = phl[wl | pre];
        const float* er = eta_new + r * K;               // L2-resident (1 MB)
        float ept = er[pt], ep1 = er[p1], epre = er[pre];
        float a1 = jexp(pa) / jexp(pb);
        bool acc1 = u0 < a1;
        int   k1  = acc1 ? p1  : pre;
        float ek1 = acc1 ? ep1 : epre;
        float a2 = jexp(ept) / jexp(ek1);
        int z = (u1 < a2) ? pt : k1;
        z_out[r * NN + n] = (float)z;                    // scattered plain store
        if (z != pre) {
            atomicAdd(&acc[wl | z],   1);                // LDS atomics
            atomicAdd(&acc[wl | pre], -1);
        }
    }
    __syncthreads();
    #pragma unroll
    for (int i = 0; i < 8; ++i) {
        int j = i * 256 + tid;
        CWK_new[rowbase + j] = CWK[rowbase + j] + (float)acc[j];
    }
}

// ---------------- doc-centric CDK finalize from z_out ----------------
__global__ void finalize_kernel(const int* __restrict__ Z,
                                const float* __restrict__ z_out,
                                const float* __restrict__ CDK,
                                float* __restrict__ CDK_new)
{
    int r = blockIdx.x;
    int n = threadIdx.x;
    __shared__ int h[K];
    if (n < K) h[n] = 0;
    __syncthreads();
    int pre = Z[r * NN + n];
    int z = (int)z_out[r * NN + n];
    if (z != pre) {
        atomicAdd(&h[z], 1);
        atomicAdd(&h[pre], -1);
    }
    __syncthreads();
    if (n < K) CDK_new[r * K + n] = CDK[r * K + n] + (float)h[n];
}

// ---------------- CK from CDK delta: CK + sum_d(CDK_new - CDK) ----------------
__global__ void ck_kernel(const float* __restrict__ CDK,
                          const float* __restrict__ CDK_new,
                          const float* __restrict__ CK,
                          float* __restrict__ CK_new)
{
    int t = blockIdx.x;
    int tid = threadIdx.x;
    int k = tid & 63;
    int j = tid >> 6;
    float s = 0.0f;
    for (int d = j; d < D; d += 4) {
        int idx = (t * D + d) * K + k;
        s += CDK_new[idx] - CDK[idx];                    // integer-valued: exact
    }
    __shared__ float sm[256];
    sm[tid] = s;
    __syncthreads();
    if (tid < 64)
        CK_new[t * K + tid] = CK[t * K + tid] +
            sm[tid] + sm[tid + 64] + sm[tid + 128] + sm[tid + 192];
}

// ---------------- per-(t,k) sum of exp(phi[t,:,k]) over V ----------------
__global__ void phi_colsum_kernel(const float* __restrict__ phi,
                                  float* __restrict__ S)
{
    int blk = blockIdx.x;
    int t = blk / 250;
    int vbase = (blk % 250) * 128;
    int k = threadIdx.x & 63;
    int rr = threadIdx.x >> 6;
    const float* base = phi + (size_t)t * VK;
    float s = 0.0f;
    #pragma unroll 4
    for (int it = 0; it < 32; ++it) {
        int v = vbase + it * 4 + rr;
        s += expf(base[v * K + k]);
    }
    __shared__ float sm[256];
    sm[threadIdx.x] = s;
    __syncthreads();
    if (threadIdx.x < 64) {
        float tot = sm[threadIdx.x] + sm[threadIdx.x + 64] +
                    sm[threadIdx.x + 128] + sm[threadIdx.x + 192];
        atomicAdd(&S[t * K + k], tot);
    }
}

// ---------------- phi SGLD update, all 4 time steps in registers ----------------
__global__ void phi_update_kernel(const float* __restrict__ phi,
                                  const float* __restrict__ CWKn,
                                  const float* __restrict__ CKn,
                                  const float* __restrict__ S,
                                  const float* __restrict__ noise_phi,
                                  float* __restrict__ phi_new)
{
    int idx = blockIdx.x * 256 + threadIdx.x;
    int k = idx & 63;
    const float eps = 0.01f;
    const float half_eps = 0.005f;
    const float sig = 1.0f / 1.01f;

    float p0 = phi[idx];
    float p1 = phi[idx + VK];
    float p2 = phi[idx + 2 * VK];
    float p3 = phi[idx + 3 * VK];

    float g0 = CWKn[idx]          - CKn[k]         * (expf(p0) / S[k]);
    float g1 = CWKn[idx + VK]     - CKn[K + k]     * (expf(p1) / S[K + k]);
    float g2 = CWKn[idx + 2 * VK] - CKn[2 * K + k] * (expf(p2) / S[2 * K + k]);
    float g3 = CWKn[idx + 3 * VK] - CKn[3 * K + k] * (expf(p3) / S[3 * K + k]);

    float r0 = p0 + half_eps * (g0 + 2.0f * p1 * sig - 2.0f * p0) + noise_phi[0] * eps;
    float r1 = p1 + half_eps * (g1 + p2 + r0 - 2.0f * p1)         + noise_phi[1] * eps;
    float r2 = p2 + half_eps * (g2 + p3 + r1 - 2.0f * p2)         + noise_phi[2] * eps;
    float r3 = p3 + half_eps * (g3 + r2 - p3)                      + noise_phi[3] * eps;

    phi_new[idx]          = r0;
    phi_new[idx + VK]     = r1;
    phi_new[idx + 2 * VK] = r2;
    phi_new[idx + 3 * VK] = r3;
}

extern "C" void kernel_launch(void* const* d_in, const int* in_sizes, int n_in,
                              void* d_out, int out_size, void* d_ws, size_t ws_size,
                              hipStream_t stream)
{
    const int*   W         = (const int*)  d_in[0];
    const int*   Z         = (const int*)  d_in[1];
    const int*   pwi       = (const int*)  d_in[2];
    const int*   ptop      = (const int*)  d_in[3];
    const float* u_mh      = (const float*)d_in[4];
    const float* noise_eta = (const float*)d_in[5];
    const float* noise_phi = (const float*)d_in[6];
    const float* alpha     = (const float*)d_in[7];
    const float* phi       = (const float*)d_in[8];
    const float* eta       = (const float*)d_in[9];
    const float* CDK       = (const float*)d_in[10];
    const float* CWK       = (const float*)d_in[11];
    const float* CK        = (const float*)d_in[12];

    float* out     = (float*)d_out;
    float* eta_new = out;                               // T*D*K
    float* phi_new = out + 262144;                      // T*V*K
    float* CDK_new = out + 8454144;                     // T*D*K
    float* CWK_new = out + 8716288;                     // T*V*K
    float* CK_new  = out + 16908288;                    // T*K
    float* z_out   = out + 16908544;                    // T*D*N

    // ws: [hist 4096][starts 4096][cursors 4096][S 256] | records @64KB (16MB)
    int*   hist    = (int*)d_ws;
    int*   starts  = hist + 4096;
    int*   cursors = starts + 4096;
    float* S       = (float*)(cursors + 4096);
    int4*  records = (int4*)((char*)d_ws + 65536);

    hipMemsetAsync(d_ws, 0, 65536, stream);

    eta_kernel<<<TD / 4, 256, 0, stream>>>(eta, alpha, CDK, noise_eta, eta_new);
    hist1_kernel<<<64, 256, 0, stream>>>(W, hist);
    scan_kernel<<<1, 1024, 0, stream>>>(hist, starts, cursors);
    scatter2_kernel<<<64, 256, 0, stream>>>(W, Z, pwi, ptop, u_mh, cursors, records);
    process_kernel<<<NBINS, 256, 0, stream>>>(records, phi, CWK, eta_new,
                                              hist, starts, CWK_new, z_out);
    finalize_kernel<<<TD, 256, 0, stream>>>(Z, z_out, CDK, CDK_new);
    ck_kernel<<<T, 256, 0, stream>>>(CDK, CDK_new, CK, CK_new);
    phi_colsum_kernel<<<T * 250, 256, 0, stream>>>(phi, S);
    phi_update_kernel<<<VK / 256, 256, 0, stream>>>(phi, CWK_new, CK_new, S,
                                                    noise_phi, phi_new);
}

// Round 5
// 388.377 us; speedup vs baseline: 1.3976x; 1.0955x over previous
//
#include <hip/hip_runtime.h>

#define T 4
#define D 1024
#define NN 256
#define K 64
#define V 32000
#define VK (V*K)            // 2048000
#define TD (T*D)            // 4096
#define NTOK (TD*NN)        // 1048576
#define NG 1000             // V/32 w-groups per t
#define NBINS (T*NG)        // 4000
#define SCB 128             // scatter blocks
#define DOCS_SC (TD/SCB)    // 32 docs per scatter block (one t per block)
#define TPB_SC (DOCS_SC*NN) // 8192 tokens per scatter block

__device__ __forceinline__ float jexp(float x) {
    x = fminf(fmaxf(x, -700.0f), 700.0f);
    return fmaxf(expf(x), 1e-6f);
}

// ---------------- eta SGLD update: one wave per (t,d) row ----------------
__global__ void eta_kernel(const float* __restrict__ eta,
                           const float* __restrict__ alpha,
                           const float* __restrict__ CDK,
                           const float* __restrict__ noise_eta,
                           float* __restrict__ eta_new)
{
    int wave = threadIdx.x >> 6;
    int lane = threadIdx.x & 63;
    int r = blockIdx.x * 4 + wave;
    int t = r >> 10;
    float x = eta[r * K + lane];
    float m = x;
    #pragma unroll
    for (int off = 32; off >= 1; off >>= 1)
        m = fmaxf(m, __shfl_xor(m, off, 64));
    float e = expf(x - m);
    float s = e;
    #pragma unroll
    for (int off = 32; off >= 1; off >>= 1)
        s += __shfl_xor(s, off, 64);
    float grad  = CDK[r * K + lane] - (float)NN * (e / s);
    float prior = alpha[t * K + lane] - x;
    eta_new[r * K + lane] = x + 0.005f * (grad + prior) + noise_eta[r] * 0.01f;
}

// ---------------- local counting sort: NO global atomics, NO inner barriers --
// 128 blocks x 32 docs (8192 tokens), each with a private records segment.
// Per-block LDS hist over 1000 w-groups -> LDS scan -> starts table publish.
__global__ __launch_bounds__(256) void scatter3_kernel(
        const int* __restrict__ W, const int* __restrict__ Z,
        const int* __restrict__ pwi, const int* __restrict__ ptop,
        const float* __restrict__ u,
        int* __restrict__ starts_t,          // [SCB][NG] global record positions
        int4* __restrict__ records)
{
    __shared__ int hist_l[1024];
    __shared__ int base_l[1024];
    __shared__ int wsum[4];
    int tid = threadIdx.x;
    int blk = blockIdx.x;
    int doc0 = blk * DOCS_SC;
    int tok0 = blk * TPB_SC;

    for (int i = tid; i < 1024; i += 256) hist_l[i] = 0;
    __syncthreads();
    // count
    for (int j = 0; j < DOCS_SC; ++j) {
        int w = W[tok0 + j * 256 + tid];
        atomicAdd(&hist_l[w >> 5], 1);
    }
    __syncthreads();
    // exclusive scan of 1024 bins (4 per thread + block scan of 256)
    int b0 = tid * 4;
    int v0 = hist_l[b0], v1 = hist_l[b0 + 1], v2 = hist_l[b0 + 2], v3 = hist_l[b0 + 3];
    int s4 = v0 + v1 + v2 + v3;
    int lane = tid & 63, wv = tid >> 6;
    int x = s4;
    #pragma unroll
    for (int off = 1; off < 64; off <<= 1) {
        int y = __shfl_up(x, off, 64);
        if (lane >= off) x += y;
    }
    if (lane == 63) wsum[wv] = x;
    __syncthreads();
    int wbase = 0;
    #pragma unroll
    for (int i = 0; i < 4; ++i) if (i < wv) wbase += wsum[i];
    int excl = wbase + x - s4;
    base_l[b0]     = excl;
    base_l[b0 + 1] = excl + v0;
    base_l[b0 + 2] = excl + v0 + v1;
    base_l[b0 + 3] = excl + v0 + v1 + v2;
    __syncthreads();
    // publish starts table (coalesced), reset hist for rank counters
    for (int i = tid; i < NG; i += 256) starts_t[blk * NG + i] = tok0 + base_l[i];
    for (int i = tid; i < 1024; i += 256) hist_l[i] = 0;
    __syncthreads();
    // token loop: fully independent iterations, no barriers
    #pragma unroll 4
    for (int j = 0; j < DOCS_SC; ++j) {
        int r = doc0 + j;
        int idx = r * NN + tid;
        int w   = W[idx];
        int pre = Z[idx];
        int p1  = Z[r * NN + pwi[idx]];      // 1KB row, L1-resident
        int pt  = ptop[idx];
        float2 uu = ((const float2*)u)[idx];
        int bin = w >> 5;
        int rank = atomicAdd(&hist_l[bin], 1);           // LDS atomic
        int pos = tok0 + base_l[bin] + rank;
        int a = (pre << 20) | (r << 8) | tid;
        int b = (w << 12) | (p1 << 6) | pt;
        records[pos] = make_int4(a, b, __float_as_int(uu.x), __float_as_int(uu.y));
    }
}

// ---------------- MH + CWK delta + fused colsum partial --------------------
// one block per (t, 32-word window); segments come from the 32 scatter blocks of t.
__global__ __launch_bounds__(256) void process_kernel(
        const int4* __restrict__ records, const float* __restrict__ phi,
        const float* __restrict__ CWK, const float* __restrict__ eta_new,
        const int* __restrict__ starts_t,
        float* __restrict__ CWK_new, float* __restrict__ z_out,
        float* __restrict__ Spart)
{
    __shared__ float phl[2048];      // 32 words x 64 topics
    __shared__ int   acc[2048];
    __shared__ float red[256];
    __shared__ int   seg_s[32], seg_c[32];
    int b = blockIdx.x;              // 0..3999
    int t = b / NG;
    int wg = b % NG;
    size_t rowbase = ((size_t)t * V + (size_t)wg * 32) * K;
    int tid = threadIdx.x;
    #pragma unroll
    for (int i = 0; i < 8; ++i) {
        phl[i * 256 + tid] = phi[rowbase + i * 256 + tid];
        acc[i * 256 + tid] = 0;
    }
    if (tid < 32) {
        int row = t * 32 + tid;                          // scatter block id
        int s = starts_t[row * NG + wg];
        int e = (wg < NG - 1) ? starts_t[row * NG + wg + 1] : (row + 1) * TPB_SC;
        seg_s[tid] = s; seg_c[tid] = e - s;
    }
    __syncthreads();
    // fused colsum partial: k = tid&63, 8 of the 32 rows each
    {
        int k = tid & 63, r0 = tid >> 6;
        float s = 0.0f;
        #pragma unroll
        for (int j = 0; j < 8; ++j) s += expf(phl[(r0 + 4 * j) * 64 + k]);
        red[tid] = s;
    }
    // token processing: 4 threads per segment
    if (tid < 128) {
        int seg = tid >> 2, par = tid & 3;
        int s0 = seg_s[seg], c = seg_c[seg];
        for (int i = par; i < c; i += 4) {
            int4 rec = records[s0 + i];
            int a = rec.x, bb = rec.y;
            float u0 = __int_as_float(rec.z), u1 = __int_as_float(rec.w);
            int pre = (a >> 20) & 63;
            int r   = (a >> 8) & 4095;
            int n   = a & 255;
            int w   = (bb >> 12) & 32767;
            int p1  = (bb >> 6) & 63;
            int pt  = bb & 63;
            int wl  = (w & 31) << 6;
            const float* er = eta_new + r * K;
            float ept = er[pt], ep1 = er[p1], epre = er[pre];
            float a1 = jexp(phl[wl | p1]) / jexp(phl[wl | pre]);
            bool acc1 = u0 < a1;
            int   k1  = acc1 ? p1  : pre;
            float ek1 = acc1 ? ep1 : epre;
            float a2 = jexp(ept) / jexp(ek1);
            int z = (u1 < a2) ? pt : k1;
            z_out[r * NN + n] = (float)z;
            if (z != pre) {
                atomicAdd(&acc[wl | z],   1);
                atomicAdd(&acc[wl | pre], -1);
            }
        }
    }
    __syncthreads();
    if (tid < 64)
        Spart[b * 64 + tid] = red[tid] + red[tid + 64] + red[tid + 128] + red[tid + 192];
    #pragma unroll
    for (int i = 0; i < 8; ++i) {
        int j = i * 256 + tid;
        CWK_new[rowbase + j] = CWK[rowbase + j] + (float)acc[j];
    }
}

// ---------------- reduce colsum partials: S[t,k] = sum_wg Spart ------------
__global__ void sreduce_kernel(const float* __restrict__ Spart,
                               float* __restrict__ S)
{
    int t = blockIdx.x;
    int tid = threadIdx.x;
    int k = tid & 63, j = tid >> 6;
    float s = 0.0f;
    for (int i = j; i < NG; i += 4) s += Spart[(t * NG + i) * 64 + k];
    __shared__ float sm[256];
    sm[tid] = s;
    __syncthreads();
    if (tid < 64)
        S[t * K + tid] = sm[tid] + sm[tid + 64] + sm[tid + 128] + sm[tid + 192];
}

// ---------------- doc-centric CDK finalize from z_out ----------------
__global__ void finalize_kernel(const int* __restrict__ Z,
                                const float* __restrict__ z_out,
                                const float* __restrict__ CDK,
                                float* __restrict__ CDK_new)
{
    int r = blockIdx.x;
    int n = threadIdx.x;
    __shared__ int h[K];
    if (n < K) h[n] = 0;
    __syncthreads();
    int pre = Z[r * NN + n];
    int z = (int)z_out[r * NN + n];
    if (z != pre) {
        atomicAdd(&h[z], 1);
        atomicAdd(&h[pre], -1);
    }
    __syncthreads();
    if (n < K) CDK_new[r * K + n] = CDK[r * K + n] + (float)h[n];
}

// ---------------- CK from CDK delta: CK + sum_d(CDK_new - CDK) ----------------
__global__ void ck_kernel(const float* __restrict__ CDK,
                          const float* __restrict__ CDK_new,
                          const float* __restrict__ CK,
                          float* __restrict__ CK_new)
{
    int t = blockIdx.x;
    int tid = threadIdx.x;
    int k = tid & 63;
    int j = tid >> 6;
    float s = 0.0f;
    for (int d = j; d < D; d += 4) {
        int idx = (t * D + d) * K + k;
        s += CDK_new[idx] - CDK[idx];
    }
    __shared__ float sm[256];
    sm[tid] = s;
    __syncthreads();
    if (tid < 64)
        CK_new[t * K + tid] = CK[t * K + tid] +
            sm[tid] + sm[tid + 64] + sm[tid + 128] + sm[tid + 192];
}

// ---------------- phi SGLD update, all 4 time steps in registers ----------------
__global__ void phi_update_kernel(const float* __restrict__ phi,
                                  const float* __restrict__ CWKn,
                                  const float* __restrict__ CKn,
                                  const float* __restrict__ S,
                                  const float* __restrict__ noise_phi,
                                  float* __restrict__ phi_new)
{
    int idx = blockIdx.x * 256 + threadIdx.x;
    int k = idx & 63;
    const float eps = 0.01f;
    const float half_eps = 0.005f;
    const float sig = 1.0f / 1.01f;

    float p0 = phi[idx];
    float p1 = phi[idx + VK];
    float p2 = phi[idx + 2 * VK];
    float p3 = phi[idx + 3 * VK];

    float g0 = CWKn[idx]          - CKn[k]         * (expf(p0) / S[k]);
    float g1 = CWKn[idx + VK]     - CKn[K + k]     * (expf(p1) / S[K + k]);
    float g2 = CWKn[idx + 2 * VK] - CKn[2 * K + k] * (expf(p2) / S[2 * K + k]);
    float g3 = CWKn[idx + 3 * VK] - CKn[3 * K + k] * (expf(p3) / S[3 * K + k]);

    float r0 = p0 + half_eps * (g0 + 2.0f * p1 * sig - 2.0f * p0) + noise_phi[0] * eps;
    float r1 = p1 + half_eps * (g1 + p2 + r0 - 2.0f * p1)         + noise_phi[1] * eps;
    float r2 = p2 + half_eps * (g2 + p3 + r1 - 2.0f * p2)         + noise_phi[2] * eps;
    float r3 = p3 + half_eps * (g3 + r2 - p3)                      + noise_phi[3] * eps;

    phi_new[idx]          = r0;
    phi_new[idx + VK]     = r1;
    phi_new[idx + 2 * VK] = r2;
    phi_new[idx + 3 * VK] = r3;
}

extern "C" void kernel_launch(void* const* d_in, const int* in_sizes, int n_in,
                              void* d_out, int out_size, void* d_ws, size_t ws_size,
                              hipStream_t stream)
{
    const int*   W         = (const int*)  d_in[0];
    const int*   Z         = (const int*)  d_in[1];
    const int*   pwi       = (const int*)  d_in[2];
    const int*   ptop      = (const int*)  d_in[3];
    const float* u_mh      = (const float*)d_in[4];
    const float* noise_eta = (const float*)d_in[5];
    const float* noise_phi = (const float*)d_in[6];
    const float* alpha     = (const float*)d_in[7];
    const float* phi       = (const float*)d_in[8];
    const float* eta       = (const float*)d_in[9];
    const float* CDK       = (const float*)d_in[10];
    const float* CWK       = (const float*)d_in[11];
    const float* CK        = (const float*)d_in[12];

    float* out     = (float*)d_out;
    float* eta_new = out;                               // T*D*K
    float* phi_new = out + 262144;                      // T*V*K
    float* CDK_new = out + 8454144;                     // T*D*K
    float* CWK_new = out + 8716288;                     // T*V*K
    float* CK_new  = out + 16908288;                    // T*K
    float* z_out   = out + 16908544;                    // T*D*N

    // d_ws: records (16 MB) | S (256 floats)
    int4*  records = (int4*)d_ws;
    float* S       = (float*)((char*)d_ws + (size_t)NTOK * 16);

    // scratch hosted in not-yet-written output regions (stream-ordered safe):
    int*   starts_t = (int*)phi_new;    // 128*1000 ints, consumed before phi_update
    float* Spart    = CDK_new;          // 4000*64 floats, consumed before finalize

    eta_kernel<<<TD / 4, 256, 0, stream>>>(eta, alpha, CDK, noise_eta, eta_new);
    scatter3_kernel<<<SCB, 256, 0, stream>>>(W, Z, pwi, ptop, u_mh,
                                             starts_t, records);
    process_kernel<<<NBINS, 256, 0, stream>>>(records, phi, CWK, eta_new,
                                              starts_t, CWK_new, z_out, Spart);
    sreduce_kernel<<<T, 256, 0, stream>>>(Spart, S);
    finalize_kernel<<<TD, 256, 0, stream>>>(Z, z_out, CDK, CDK_new);
    ck_kernel<<<T, 256, 0, stream>>>(CDK, CDK_new, CK, CK_new);
    phi_update_kernel<<<VK / 256, 256, 0, stream>>>(phi, CWK_new, CK_new, S,
                                                    noise_phi, phi_new);
}